// Round 4
// baseline (1891.140 us; speedup 1.0000x reference)
//
#include <hip/hip_runtime.h>

// Precoding GNN: 5 layers of z = Ws*x + Wm*(sum_k x) + Wk*(sum_m x), ReLU(1-4),
// then Frobenius power normalization per batch item.
// M=64 antennas, K=32 users, D=32 hidden, BS=1024.
//
// One 1024-thread block per batch item. Thread t owns nodes t and t+1024
// (node n = m*32+k), features in registers, fp32 end-to-end.
//
// R1: default launch_bounds -> 64-VGPR budget -> spill -> 34 GB HBM.
// R2: float[32] allocas not promoted; ext_vector + SGPR weights helped but
// R3: VGPR_Count STILL 64 -> __launch_bounds__(1024,4) only sets a *floor*
//   on waves/EU; the backend's occupancy heuristic still targeted 8/EU and
//   spilled to a 64-VGPR budget. Fix: amdgpu_waves_per_eu(4,4) pins min AND
//   max -> 128-VGPR budget; peak live set ~110 fits.

namespace {

constexpr int NTHREADS = 1024;
constexpr int LD = 34;   // LDS row stride: 8B-aligned (float2), bank stride 2 -> conflict-free

typedef float vf32 __attribute__((ext_vector_type(32)));

template <int DIN, int DOUT, bool RELU>
__device__ __forceinline__ void gnn_layer_dev(
    vf32& x1, vf32& x2,
    const float* __restrict__ Wsg, const float* __restrict__ Wmg,
    const float* __restrict__ Wkg,
    float* __restrict__ Wm_l,   // [32*LD]
    float* __restrict__ Wk_l,   // [32*LD]
    float* __restrict__ Abuf,   // [64*LD]
    float* __restrict__ Bbuf,   // [32*LD]
    float* __restrict__ msgk,   // [32*LD]
    int t, int k, int m1, int m2, int lane)
{
    // ---- phase 0: stage Wm/Wk to LDS (per-lane-row access later), zero msgk ----
    for (int i = t; i < DOUT * DIN; i += NTHREADS) {
        const int h = i / DIN, d = i % DIN;
        Wm_l[h * LD + d] = Wmg[i];
        Wk_l[h * LD + d] = Wkg[i];
    }
    for (int i = t; i < 32 * LD; i += NTHREADS) msgk[i] = 0.0f;
    __syncthreads();

    // ---- phase 1a: msg_k contribution (register-light first) ----
    // Thread holds antennas m1, m1+32 for user k; lane^32 holds the m1^1 pair;
    // 16 waves cover all 64 antennas via LDS ds_add_f32.
#pragma unroll
    for (int d = 0; d < DIN; ++d) {
        float s = x1[d] + x2[d];
        s += __shfl_xor(s, 32);
        if (lane < 32) atomicAdd(&msgk[k * LD + d], s);
    }

    // ---- phase 1b: msg_m butterfly per node, fused A[m][k] = Wm[k,:].msg_m ----
    {
        vf32 mm = x1;
#pragma unroll
        for (int mask = 1; mask <= 16; mask <<= 1) {
#pragma unroll
            for (int d = 0; d < DIN; ++d) mm[d] += __shfl_xor(mm[d], mask);
        }
        if (k < DOUT) {
            const float2* wr = reinterpret_cast<const float2*>(Wm_l + k * LD);
            float acc = 0.0f;
#pragma unroll
            for (int q = 0; q < (DIN + 1) / 2; ++q) {
                const float2 w = wr[q];
                acc += w.x * mm[2 * q];
                if (2 * q + 1 < DIN) acc += w.y * mm[2 * q + 1];
            }
            Abuf[m1 * LD + k] = acc;
        }
    }
    {
        vf32 mm = x2;
#pragma unroll
        for (int mask = 1; mask <= 16; mask <<= 1) {
#pragma unroll
            for (int d = 0; d < DIN; ++d) mm[d] += __shfl_xor(mm[d], mask);
        }
        if (k < DOUT) {
            const float2* wr = reinterpret_cast<const float2*>(Wm_l + k * LD);
            float acc = 0.0f;
#pragma unroll
            for (int q = 0; q < (DIN + 1) / 2; ++q) {
                const float2 w = wr[q];
                acc += w.x * mm[2 * q];
                if (2 * q + 1 < DIN) acc += w.y * mm[2 * q + 1];
            }
            Abuf[m2 * LD + k] = acc;
        }
    }
    __syncthreads();

    // ---- phase 2: B[k][h] = Wk[h,:].msg_k ----
    if (t < 32 * DOUT) {
        const int kk = t / DOUT, hh = t % DOUT;
        const float2* wr = reinterpret_cast<const float2*>(Wk_l + hh * LD);
        const float2* mr = reinterpret_cast<const float2*>(msgk + kk * LD);
        float acc = 0.0f;
#pragma unroll
        for (int q = 0; q < (DIN + 1) / 2; ++q) {
            const float2 w = wr[q];
            const float2 m = mr[q];
            acc += w.x * m.x;
            if (2 * q + 1 < DIN) acc += w.y * m.y;
        }
        Bbuf[kk * LD + hh] = acc;
    }
    __syncthreads();

    // ---- phase 3: per-node z[h] = Ws[h,:].x + A[m][h] + B[k][h]; Ws read
    //      straight from global (uniform address -> scalar loads/SGPRs) ----
    {
        vf32 z;
        const float2* ar = reinterpret_cast<const float2*>(Abuf + m1 * LD);
        const float2* br = reinterpret_cast<const float2*>(Bbuf + k * LD);
#pragma unroll
        for (int hq = 0; hq < DOUT / 2; ++hq) {
            const float2 av = ar[hq];
            const float2 bv = br[hq];
            float acc0 = av.x + bv.x;
            float acc1 = av.y + bv.y;
#pragma unroll
            for (int d = 0; d < DIN; ++d) {
                const float xd = x1[d];
                acc0 += Wsg[(2 * hq) * DIN + d] * xd;
                acc1 += Wsg[(2 * hq + 1) * DIN + d] * xd;
            }
            z[2 * hq]     = RELU ? fmaxf(acc0, 0.0f) : acc0;
            z[2 * hq + 1] = RELU ? fmaxf(acc1, 0.0f) : acc1;
        }
        x1 = z;
    }
    {
        vf32 z;
        const float2* ar = reinterpret_cast<const float2*>(Abuf + m2 * LD);
        const float2* br = reinterpret_cast<const float2*>(Bbuf + k * LD);
#pragma unroll
        for (int hq = 0; hq < DOUT / 2; ++hq) {
            const float2 av = ar[hq];
            const float2 bv = br[hq];
            float acc0 = av.x + bv.x;
            float acc1 = av.y + bv.y;
#pragma unroll
            for (int d = 0; d < DIN; ++d) {
                const float xd = x2[d];
                acc0 += Wsg[(2 * hq) * DIN + d] * xd;
                acc1 += Wsg[(2 * hq + 1) * DIN + d] * xd;
            }
            z[2 * hq]     = RELU ? fmaxf(acc0, 0.0f) : acc0;
            z[2 * hq + 1] = RELU ? fmaxf(acc1, 0.0f) : acc1;
        }
        x2 = z;
    }
    __syncthreads();  // protect Wm/Wk/msgk before next layer restages
}

__global__
__attribute__((amdgpu_flat_work_group_size(NTHREADS, NTHREADS), amdgpu_waves_per_eu(4, 4)))
void gnn_fused(
    const float* __restrict__ xg,
    const float* __restrict__ w1s, const float* __restrict__ w1m, const float* __restrict__ w1k,
    const float* __restrict__ w2s, const float* __restrict__ w2m, const float* __restrict__ w2k,
    const float* __restrict__ w3s, const float* __restrict__ w3m, const float* __restrict__ w3k,
    const float* __restrict__ w4s, const float* __restrict__ w4m, const float* __restrict__ w4k,
    const float* __restrict__ w5s, const float* __restrict__ w5m, const float* __restrict__ w5k,
    float* __restrict__ out)
{
    __shared__ float Wm_l[32 * LD];
    __shared__ float Wk_l[32 * LD];
    __shared__ float Abuf[64 * LD];
    __shared__ float Bbuf[32 * LD];
    __shared__ float msgk[32 * LD];
    __shared__ float red[17];

    const int t = threadIdx.x;
    const int b = blockIdx.x;
    const int k = t & 31;
    const int m1 = t >> 5;
    const int m2 = m1 + 32;
    const int lane = t & 63;
    const int wave = t >> 6;

    vf32 x1, x2;

    // input: (b, 64, 32, 2) -> node n covers floats [2n, 2n+1]
    const float2 a1 = *reinterpret_cast<const float2*>(xg + (size_t)b * 4096 + 2 * t);
    const float2 a2 = *reinterpret_cast<const float2*>(xg + (size_t)b * 4096 + 2048 + 2 * t);
    x1[0] = a1.x; x1[1] = a1.y;
    x2[0] = a2.x; x2[1] = a2.y;

    gnn_layer_dev<2, 32, true>(x1, x2, w1s, w1m, w1k,
                               Wm_l, Wk_l, Abuf, Bbuf, msgk, t, k, m1, m2, lane);
    gnn_layer_dev<32, 32, true>(x1, x2, w2s, w2m, w2k,
                                Wm_l, Wk_l, Abuf, Bbuf, msgk, t, k, m1, m2, lane);
    gnn_layer_dev<32, 32, true>(x1, x2, w3s, w3m, w3k,
                                Wm_l, Wk_l, Abuf, Bbuf, msgk, t, k, m1, m2, lane);
    gnn_layer_dev<32, 32, true>(x1, x2, w4s, w4m, w4k,
                                Wm_l, Wk_l, Abuf, Bbuf, msgk, t, k, m1, m2, lane);
    gnn_layer_dev<32, 2, false>(x1, x2, w5s, w5m, w5k,
                                Wm_l, Wk_l, Abuf, Bbuf, msgk, t, k, m1, m2, lane);

    // ---- pwr_norm: alpha = rsqrt(sum over all (m,k,c) of z^2) ----
    float p = x1[0] * x1[0] + x1[1] * x1[1] + x2[0] * x2[0] + x2[1] * x2[1];
#pragma unroll
    for (int mask = 1; mask <= 32; mask <<= 1) p += __shfl_xor(p, mask);
    if (lane == 0) red[wave] = p;
    __syncthreads();
    if (t == 0) {
        float tot = 0.0f;
#pragma unroll
        for (int i = 0; i < 16; ++i) tot += red[i];
        red[16] = rsqrtf(tot);
    }
    __syncthreads();
    const float alpha = red[16];

    float2 o1, o2;
    o1.x = alpha * x1[0]; o1.y = alpha * x1[1];
    o2.x = alpha * x2[0]; o2.y = alpha * x2[1];
    *reinterpret_cast<float2*>(out + (size_t)b * 4096 + 2 * t) = o1;
    *reinterpret_cast<float2*>(out + (size_t)b * 4096 + 2048 + 2 * t) = o2;
}

}  // namespace

extern "C" void kernel_launch(void* const* d_in, const int* in_sizes, int n_in,
                              void* d_out, int out_size, void* d_ws, size_t ws_size,
                              hipStream_t stream) {
    const float* xg  = (const float*)d_in[0];
    const float* w1s = (const float*)d_in[1];
    const float* w1m = (const float*)d_in[2];
    const float* w1k = (const float*)d_in[3];
    const float* w2s = (const float*)d_in[4];
    const float* w2m = (const float*)d_in[5];
    const float* w2k = (const float*)d_in[6];
    const float* w3s = (const float*)d_in[7];
    const float* w3m = (const float*)d_in[8];
    const float* w3k = (const float*)d_in[9];
    const float* w4s = (const float*)d_in[10];
    const float* w4m = (const float*)d_in[11];
    const float* w4k = (const float*)d_in[12];
    const float* w5s = (const float*)d_in[13];
    const float* w5m = (const float*)d_in[14];
    const float* w5k = (const float*)d_in[15];
    float* out = (float*)d_out;

    hipLaunchKernelGGL(gnn_fused, dim3(1024), dim3(NTHREADS), 0, stream,
                       xg, w1s, w1m, w1k, w2s, w2m, w2k, w3s, w3m, w3k,
                       w4s, w4m, w4k, w5s, w5m, w5k, out);
}